// Round 1
// baseline (378.100 us; speedup 1.0000x reference)
//
#include <hip/hip_runtime.h>

// MultiLabelSoftMax: B=4096 rows, C=8192 classes, K=8 positives/row.
// out = (1/(B*K)) * sum_{b,k} [ log(exp(p_bk) + sum_neg_b) - p_bk ]
// where sum_neg_b = sum_c exp(pred[b,c]) - sum_k exp(p_bk).
//
// Round-2 structure: SINGLE fused kernel. Each block computes one row's term
// and writes partial[b]; the last block to finish (device-scope atomic counter)
// performs the 4096-element final reduction. Counter is zeroed by a 4-byte
// hipMemsetAsync (graph-capturable; harness uses the same primitive).
//
// Cross-XCD coherence: writer does __threadfence() (agent-release: L2 writeback)
// before the atomicAdd; the last block does __threadfence() (agent-acquire:
// L2 invalidate) after observing count==B-1, before reading partial[].

constexpr int B = 4096;
constexpr int C = 8192;
constexpr int K = 8;
constexpr int BLOCK = 256;                 // 4 waves of 64
constexpr int VPT = C / 4 / BLOCK;         // 8 float4 per thread

__global__ __launch_bounds__(BLOCK)
void mlsm_fused_kernel(const float* __restrict__ pred,
                       const int* __restrict__ labels,
                       float* __restrict__ partial,
                       unsigned int* __restrict__ counter,
                       float* __restrict__ out) {
    const int b   = blockIdx.x;
    const int tid = threadIdx.x;
    const float* row = pred + (size_t)b * C;
    const float4* row4 = reinterpret_cast<const float4*>(row);

    // Hoist the label gather to the top: the labels load and the dependent
    // row[cls] gather issue before/with the streaming loads, so the epilogue
    // has no dependent-load chain left in the block tail.
    int   cls = 0;
    float p   = 0.f;
    if (tid < K) {
        cls = labels[b * K + tid];
        p   = row[cls];
    }

    // Prefetch all 8 float4 (32 elems): 8 independent loads in flight.
    float4 v[VPT];
#pragma unroll
    for (int i = 0; i < VPT; ++i)
        v[i] = row4[tid + i * BLOCK];

    // 4-way split accumulators for exp ILP.
    float s0 = 0.f, s1 = 0.f, s2 = 0.f, s3 = 0.f;
#pragma unroll
    for (int i = 0; i < VPT; ++i) {
        s0 += __expf(v[i].x);
        s1 += __expf(v[i].y);
        s2 += __expf(v[i].z);
        s3 += __expf(v[i].w);
    }
    float s = (s0 + s1) + (s2 + s3);

    // wave64 shuffle reduction
#pragma unroll
    for (int off = 32; off > 0; off >>= 1)
        s += __shfl_down(s, off, 64);

    __shared__ float wave_sum[BLOCK / 64];
    __shared__ bool  is_last;
    if ((tid & 63) == 0) wave_sum[tid >> 6] = s;
    __syncthreads();

    // Epilogue on lanes 0..7: one positive each, butterfly over width-8 group.
    if (tid < K) {
        const float total =
            (wave_sum[0] + wave_sum[1]) + (wave_sum[2] + wave_sum[3]);

        const float e = __expf(p);

        float sum_pos = e;
#pragma unroll
        for (int m = 1; m < K; m <<= 1)
            sum_pos += __shfl_xor(sum_pos, m, K);

        const float sum_neg = total - sum_pos;
        float term = __logf(e + sum_neg) - p;
#pragma unroll
        for (int m = 1; m < K; m <<= 1)
            term += __shfl_xor(term, m, K);

        if (tid == 0) {
            partial[b] = term;
            __threadfence();                         // release: drain + L2 writeback
            const unsigned int done = atomicAdd(counter, 1u);
            is_last = (done == (unsigned int)(B - 1));
        }
    }
    __syncthreads();          // is_last ready; also orders wave_sum reuse below
    if (!is_last) return;

    // ---- last block: final reduction over partial[0..B-1] ----
    __threadfence();          // acquire: invalidate L1/L2 before reading partials

    const float4* p4 = reinterpret_cast<const float4*>(partial);
    float r = 0.f;
#pragma unroll
    for (int i = 0; i < B / 4 / BLOCK; ++i) {   // 4 float4 per thread
        float4 q = p4[tid + i * BLOCK];
        r += (q.x + q.y) + (q.z + q.w);
    }
#pragma unroll
    for (int off = 32; off > 0; off >>= 1)
        r += __shfl_down(r, off, 64);

    if ((tid & 63) == 0) wave_sum[tid >> 6] = r;
    __syncthreads();

    if (tid == 0)
        out[0] = ((wave_sum[0] + wave_sum[1]) + (wave_sum[2] + wave_sum[3]))
                 * (1.0f / (float)(B * K));
}

extern "C" void kernel_launch(void* const* d_in, const int* in_sizes, int n_in,
                              void* d_out, int out_size, void* d_ws, size_t ws_size,
                              hipStream_t stream) {
    const float* pred = (const float*)d_in[0];
    const int* labels = (const int*)d_in[1];
    float* out        = (float*)d_out;
    float* partial    = (float*)d_ws;                     // 4096 floats = 16 KiB
    unsigned int* cnt = (unsigned int*)((char*)d_ws + B * sizeof(float)); // 128B-aligned

    hipMemsetAsync(cnt, 0, sizeof(unsigned int), stream); // zero poisoned counter
    mlsm_fused_kernel<<<B, BLOCK, 0, stream>>>(pred, labels, partial, cnt, out);
}

// Round 2
// 189.254 us; speedup vs baseline: 1.9978x; 1.9978x over previous
//
#include <hip/hip_runtime.h>

// MultiLabelSoftMax: B=4096 rows, C=8192 classes, K=8 positives/row.
// out = (1/(B*K)) * sum_{b,k} [ log(exp(p_bk) + sum_neg_b) - p_bk ]
// where sum_neg_b = sum_c exp(pred[b,c]) - sum_k exp(p_bk).
//
// Round-3: REVERT to the two-kernel structure (kernel1: one block per row ->
// partial loss; kernel2: single block reduces 4096 partials). The round-2
// fused single-kernel variant regressed 190->378 us: per-block device-scope
// __threadfence + same-address device atomic serialize at the cross-XCD
// coherence point (234 us in-kernel, VALUBusy 2%, 3.6% HBM).
// Kept from round-2: label/positive gather hoisted above the streaming loads
// so the dependent load chain overlaps the bulk row stream.

constexpr int B = 4096;
constexpr int C = 8192;
constexpr int K = 8;
constexpr int BLOCK = 256;                 // 4 waves of 64
constexpr int VPT = C / 4 / BLOCK;         // 8 float4 per thread

__global__ __launch_bounds__(BLOCK)
void mlsm_row_kernel(const float* __restrict__ pred,
                     const int* __restrict__ labels,
                     float* __restrict__ partial) {
    const int b   = blockIdx.x;
    const int tid = threadIdx.x;
    const float* row = pred + (size_t)b * C;
    const float4* row4 = reinterpret_cast<const float4*>(row);

    // Hoist the label gather: labels load + dependent row[cls] gather issue
    // with the streaming loads instead of sitting in the block tail.
    float p = 0.f;
    if (tid < K) {
        const int cls = labels[b * K + tid];
        p = row[cls];
    }

    // Prefetch all 8 float4 (32 elems): 8 independent loads in flight.
    float4 v[VPT];
#pragma unroll
    for (int i = 0; i < VPT; ++i)
        v[i] = row4[tid + i * BLOCK];

    // 4-way split accumulators for exp ILP.
    float s0 = 0.f, s1 = 0.f, s2 = 0.f, s3 = 0.f;
#pragma unroll
    for (int i = 0; i < VPT; ++i) {
        s0 += __expf(v[i].x);
        s1 += __expf(v[i].y);
        s2 += __expf(v[i].z);
        s3 += __expf(v[i].w);
    }
    float s = (s0 + s1) + (s2 + s3);

    // wave64 shuffle reduction
#pragma unroll
    for (int off = 32; off > 0; off >>= 1)
        s += __shfl_down(s, off, 64);

    __shared__ float wave_sum[BLOCK / 64];
    if ((tid & 63) == 0) wave_sum[tid >> 6] = s;
    __syncthreads();

    // Epilogue on lanes 0..7: one positive each, butterfly over width-8 group.
    if (tid < K) {
        const float total =
            (wave_sum[0] + wave_sum[1]) + (wave_sum[2] + wave_sum[3]);

        const float e = __expf(p);

        float sum_pos = e;
#pragma unroll
        for (int m = 1; m < K; m <<= 1)
            sum_pos += __shfl_xor(sum_pos, m, K);

        const float sum_neg = total - sum_pos;
        float term = __logf(e + sum_neg) - p;
#pragma unroll
        for (int m = 1; m < K; m <<= 1)
            term += __shfl_xor(term, m, K);

        if (tid == 0) partial[b] = term;
    }
}

__global__ __launch_bounds__(BLOCK)
void mlsm_reduce_kernel(const float* __restrict__ partial,
                        float* __restrict__ out) {
    const int tid = threadIdx.x;
    const float4* p4 = reinterpret_cast<const float4*>(partial);

    float s = 0.f;
#pragma unroll
    for (int i = 0; i < B / 4 / BLOCK; ++i) {   // 4 float4 per thread
        float4 v = p4[tid + i * BLOCK];
        s += (v.x + v.y) + (v.z + v.w);
    }
#pragma unroll
    for (int off = 32; off > 0; off >>= 1)
        s += __shfl_down(s, off, 64);

    __shared__ float wave_sum[BLOCK / 64];
    if ((tid & 63) == 0) wave_sum[tid >> 6] = s;
    __syncthreads();

    if (tid == 0)
        out[0] = ((wave_sum[0] + wave_sum[1]) + (wave_sum[2] + wave_sum[3]))
                 * (1.0f / (float)(B * K));
}

extern "C" void kernel_launch(void* const* d_in, const int* in_sizes, int n_in,
                              void* d_out, int out_size, void* d_ws, size_t ws_size,
                              hipStream_t stream) {
    const float* pred = (const float*)d_in[0];
    const int* labels = (const int*)d_in[1];
    float* out        = (float*)d_out;
    float* partial    = (float*)d_ws;       // 4096 floats = 16 KiB

    mlsm_row_kernel<<<B, BLOCK, 0, stream>>>(pred, labels, partial);
    mlsm_reduce_kernel<<<1, BLOCK, 0, stream>>>(partial, out);
}